// Round 8
// baseline (19109.492 us; speedup 1.0000x reference)
//
#include <hip/hip_runtime.h>

#define H 51
#define TSEQ 2048
#define BB 4             // batch per block (MFMA cols 4..15 pad) -> 512 blocks, 2 blocks/CU
#define THREADS 512      // 8 waves, 2 tile-slots each, 4 waves/SIMD (2 independent blocks)

typedef _Float16 __attribute__((ext_vector_type(8))) half8;  // 8 f16 (MFMA A/B frag)
typedef float    __attribute__((ext_vector_type(4))) float4v;

#define LOG2E    1.44269504f
#define TWOLOG2E 2.88539008f
#define INV4096  0.000244140625f

__device__ __forceinline__ float sig_pre(float u) {   // sigmoid(g), u = g*log2e
    return __builtin_amdgcn_rcpf(1.0f + __builtin_amdgcn_exp2f(-u));
}
__device__ __forceinline__ float tanh_pre(float u) {  // tanh(g),  u = g*2log2e
    return 1.0f - 2.0f * __builtin_amdgcn_rcpf(1.0f + __builtin_amdgcn_exp2f(u));
}

// R7 structure (rotated schedule, single-plane f16 h, split-f16 weights) with
// BB=4 / 512 blocks: two independent blocks per CU -> 4 waves/SIMD with
// UNCORRELATED barriers, so one block's trans burst overlaps the other's
// MFMA/LDS phases. Dummy tiles (13-15) skip elementwise (wave-uniform branch);
// their MFMA runs with zero weights into zero-A-column k-pad slots.
__global__ __launch_bounds__(THREADS, 4)
void lstm_dp_kernel(const float* __restrict__ input,
                    const float* __restrict__ W_ih1, const float* __restrict__ W_hh1,
                    const float* __restrict__ b_ih1, const float* __restrict__ b_hh1,
                    const float* __restrict__ W_ih2, const float* __restrict__ W_hh2,
                    const float* __restrict__ b_ih2, const float* __restrict__ b_hh2,
                    const float* __restrict__ W_lin, const float* __restrict__ b_lin,
                    float* __restrict__ out)
{
    // [parity][kstep][fraglane], single f16 plane; k-pad (k>=51) inert
    __shared__ half8 hb1[2][2][64];
    __shared__ half8 hb2[2][2][64];
    __shared__ float h2f[2][64 * 16];     // fp32 h2 (padded j<64) for y
    __shared__ float xss[2][64 * 5 + 16]; // x chunks [i*5+b], +16 pad for n>=4 reads
    __shared__ float ybf[BB][64];         // y buffer (wave7-private)
    __shared__ float wlin[H + 1];

    const int tid  = threadIdx.x;
    const int wv   = tid >> 6;            // 0..7
    const int lane = tid & 63;
    const int n    = lane & 15;           // MFMA col; batch if n<BB
    const int qd   = lane >> 4;           // quad
    const int b0   = blockIdx.x * BB;

    if (tid < 256) {                      // zero both parities (256 half8 per array)
        half8 z = {0,0,0,0,0,0,0,0};
        (&hb1[0][0][0])[tid] = z;
        (&hb2[0][0][0])[tid] = z;
    }
    if (tid < H)  wlin[tid] = W_lin[tid];
    if (tid == H) wlin[H]   = b_lin[0];

    // x chunk 0: 64 steps x 4 batch = 256 elems
    if (tid < 256) {
        int i = tid >> 2, b = tid & 3;
        xss[0][i * 5 + b] = input[(size_t)(b0 + b) * TSEQ + i];
    }

    // ---- persistent A-fragments, split f16 (lo pre-scaled x4096), pre-scaled gates ----
    half8 wa1h[2][2], wa1l[2][2];         // W_hh1 (K=64)
    half8 wa2h[2][4], wa2l[2][4];         // s<2: W_ih2 (k=h1); s>=2: W_hh2 (k=h2)
#pragma unroll
    for (int i = 0; i < 2; ++i) {
        const int tile = wv + 8 * i;      // tiles 13..15 dummy (zero weights)
        const int arow = tile * 16 + n;
        const int cell = arow >> 2, gate = arow & 3;
        const int orow = gate * H + cell;
        const float gsc = (gate == 2) ? TWOLOG2E : LOG2E;
        const bool rok = (arow < 4 * H);
#pragma unroll
        for (int s = 0; s < 2; ++s) {
#pragma unroll
            for (int j = 0; j < 8; ++j) {
                int kk = s * 32 + qd * 8 + j;
                float w = (rok && kk < H) ? gsc * W_hh1[orow * H + kk] : 0.f;
                _Float16 hi = (_Float16)w;
                wa1h[i][s][j] = hi;
                wa1l[i][s][j] = (_Float16)((w - (float)hi) * 4096.f);
            }
        }
#pragma unroll
        for (int s = 0; s < 4; ++s) {
#pragma unroll
            for (int j = 0; j < 8; ++j) {
                int kk = s * 32 + qd * 8 + j;
                float w = 0.f;
                if (rok) {
                    if (kk < H)                       w = gsc * W_ih2[orow * H + kk];
                    else if (kk >= 64 && kk < 64 + H) w = gsc * W_hh2[orow * H + (kk - 64)];
                }
                _Float16 hi = (_Float16)w;
                wa2h[i][s][j] = hi;
                wa2l[i][s][j] = (_Float16)((w - (float)hi) * 4096.f);
            }
        }
    }

    // ---- per-lane elementwise constants (cell j = tile*4 + quad, j<64) ----
    float4v bias1v[2], wih1v[2], bias2v[2];
    int jj[2];
    bool tok[2];
#pragma unroll
    for (int i = 0; i < 2; ++i) {
        const int tile = wv + 8 * i;
        tok[i] = (tile < 13);             // wave-uniform: real tile?
        const int j = tile * 4 + qd;
        jj[i] = j;
        const bool cok = (j < H);
#pragma unroll
        for (int r = 0; r < 4; ++r) {
            const float gsc = (r == 2) ? TWOLOG2E : LOG2E;
            const int orow = r * H + j;
            bias1v[i][r] = cok ? gsc * (b_ih1[orow] + b_hh1[orow]) : 0.f;
            wih1v[i][r]  = cok ? gsc * W_ih1[orow] : 0.f;
            bias2v[i][r] = cok ? gsc * (b_ih2[orow] + b_hh2[orow]) : 0.f;
        }
    }

    float c1[2] = {0.f, 0.f};
    float c2[2] = {0.f, 0.f};

    __syncthreads();   // zeros + wlin + x chunk 0 visible

    // ---- prologue: h1(0) = ew(bias1 + Wih1*x(0))   (h1(-1)=0 -> no MFMA) ----
    {
        const float xb = xss[0][n];       // n>=4 reads pad/x-of-other-steps: finite, inert
#pragma unroll
        for (int i = 0; i < 2; ++i) if (tok[i]) {
            float4v a;
#pragma unroll
            for (int r = 0; r < 4; ++r) a[r] = fmaf(wih1v[i][r], xb, bias1v[i][r]);
            float cn = fmaf(sig_pre(a[1]), c1[i], sig_pre(a[0]) * tanh_pre(a[2]));
            c1[i] = cn;
            float h = sig_pre(a[3]) * tanh_pre(cn * TWOLOG2E);
            int j = jj[i], s = j >> 5, q = (j & 31) >> 3, j7 = j & 7;
            ((_Float16*)&hb1[0][s][q * 16 + n])[j7] = (_Float16)h;
        }
    }
    __syncthreads();   // h1(0) published

#pragma unroll 1
    for (int t = 0; t < TSEQ; ++t) {
        const int p = t & 1;

        // mid-chunk x prefetch (barrier-free double buffer), waves 0-3 only
        if ((t & 63) == 32 && t + 32 < TSEQ && tid < 256) {
            const int cp = (t >> 6) & 1;
            int i = tid >> 2, b = tid & 3;
            xss[cp ^ 1][i * 5 + b] = input[(size_t)(b0 + b) * TSEQ + (t + 32) + i];
        }

        // ---- frag loads: h1(t) [parity p], h2(t-1) [parity p^1] — 4 b128 ----
        half8 g1[2], g2[2];
#pragma unroll
        for (int s = 0; s < 2; ++s) {
            g1[s] = hb1[p][s][lane];
            g2[s] = hb2[p ^ 1][s][lane];
        }

        // ---- y(t-1) + chunk flush: wave7 only ----
        if (wv == 7 && t > 0) {
            const int b = lane & 15, kg = lane >> 4;
            float a = 0.f;
#pragma unroll
            for (int it = 0; it < 13; ++it) {
                int j = kg + it * 4;
                if (j < H) a = fmaf(wlin[j], h2f[p ^ 1][j * 16 + b], a);
            }
            a += __shfl_xor(a, 16, 64);
            a += __shfl_xor(a, 32, 64);
            if (kg == 0 && b < BB) ybf[b][(t - 1) & 63] = a + wlin[H];
            if ((t & 63) == 0) {          // flush y[t-64 .. t-1]
                int tb = t - 64;
#pragma unroll
                for (int r = 0; r < BB; ++r)
                    out[(size_t)(b0 + r) * TSEQ + tb + lane] = ybf[r][lane];
            }
        }

        // ======== chain A: mm2(t)  (g1=h1(t), g2=h2(t-1)) ========
        float4v a2[2], a2l[2];
#pragma unroll
        for (int i = 0; i < 2; ++i) {
            a2[i]  = bias2v[i];
            a2l[i] = (float4v){0.f, 0.f, 0.f, 0.f};
        }
#pragma unroll
        for (int s = 0; s < 2; ++s)
#pragma unroll
            for (int i = 0; i < 2; ++i) {
                a2[i]  = __builtin_amdgcn_mfma_f32_16x16x32_f16(wa2h[i][s],     g1[s], a2[i],  0, 0, 0);
                a2l[i] = __builtin_amdgcn_mfma_f32_16x16x32_f16(wa2l[i][s],     g1[s], a2l[i], 0, 0, 0);
                a2[i]  = __builtin_amdgcn_mfma_f32_16x16x32_f16(wa2h[i][s + 2], g2[s], a2[i],  0, 0, 0);
                a2l[i] = __builtin_amdgcn_mfma_f32_16x16x32_f16(wa2l[i][s + 2], g2[s], a2l[i], 0, 0, 0);
            }

        // ======== chain B: mm1(t+1)  (g1=h1(t), x(t+1)) ========
        const int t1 = t + 1;
        const float xb = xss[(t1 >> 6) & 1][(t1 & 63) * 5 + n];
        float4v a1[2], a1l[2];
#pragma unroll
        for (int i = 0; i < 2; ++i) {
#pragma unroll
            for (int r = 0; r < 4; ++r)
                a1[i][r] = fmaf(wih1v[i][r], xb, bias1v[i][r]);
            a1l[i] = (float4v){0.f, 0.f, 0.f, 0.f};
        }
#pragma unroll
        for (int s = 0; s < 2; ++s)
#pragma unroll
            for (int i = 0; i < 2; ++i) {
                a1[i]  = __builtin_amdgcn_mfma_f32_16x16x32_f16(wa1h[i][s], g1[s], a1[i],  0, 0, 0);
                a1l[i] = __builtin_amdgcn_mfma_f32_16x16x32_f16(wa1l[i][s], g1[s], a1l[i], 0, 0, 0);
            }

        // ---- ew2 -> hb2[p], h2f[p] (dummy tiles skipped, wave-uniform) ----
#pragma unroll
        for (int i = 0; i < 2; ++i) if (tok[i]) {
#pragma unroll
            for (int r = 0; r < 4; ++r)
                a2[i][r] = fmaf(a2l[i][r], INV4096, a2[i][r]);
            float cn = fmaf(sig_pre(a2[i][1]), c2[i], sig_pre(a2[i][0]) * tanh_pre(a2[i][2]));
            c2[i] = cn;
            float h = sig_pre(a2[i][3]) * tanh_pre(cn * TWOLOG2E);
            int j = jj[i], s = j >> 5, q = (j & 31) >> 3, j7 = j & 7;
            ((_Float16*)&hb2[p][s][q * 16 + n])[j7] = (_Float16)h;
            h2f[p][j * 16 + n] = h;
        }

        // ---- ew1 -> hb1[p^1] ----
#pragma unroll
        for (int i = 0; i < 2; ++i) if (tok[i]) {
#pragma unroll
            for (int r = 0; r < 4; ++r)
                a1[i][r] = fmaf(a1l[i][r], INV4096, a1[i][r]);
            float cn = fmaf(sig_pre(a1[i][1]), c1[i], sig_pre(a1[i][0]) * tanh_pre(a1[i][2]));
            c1[i] = cn;
            float h = sig_pre(a1[i][3]) * tanh_pre(cn * TWOLOG2E);
            int j = jj[i], s = j >> 5, q = (j & 31) >> 3, j7 = j & 7;
            ((_Float16*)&hb1[p ^ 1][s][q * 16 + n])[j7] = (_Float16)h;
        }

        __syncthreads();   // publishes h2(t), h2f(t), h1(t+1)
    }

    // ---- epilogue: y(2047) + final chunk flush ----
    if (wv == 7) {
        const int b = lane & 15, kg = lane >> 4;
        float a = 0.f;
#pragma unroll
        for (int it = 0; it < 13; ++it) {
            int j = kg + it * 4;
            if (j < H) a = fmaf(wlin[j], h2f[1][j * 16 + b], a);
        }
        a += __shfl_xor(a, 16, 64);
        a += __shfl_xor(a, 32, 64);
        if (kg == 0 && b < BB) ybf[b][63] = a + wlin[H];
#pragma unroll
        for (int r = 0; r < BB; ++r)
            out[(size_t)(b0 + r) * TSEQ + (TSEQ - 64) + lane] = ybf[r][lane];
    }
}

extern "C" void kernel_launch(void* const* d_in, const int* in_sizes, int n_in,
                              void* d_out, int out_size, void* d_ws, size_t ws_size,
                              hipStream_t stream) {
    const float* input = (const float*)d_in[0];
    const float* W_ih1 = (const float*)d_in[1];
    const float* W_hh1 = (const float*)d_in[2];
    const float* b_ih1 = (const float*)d_in[3];
    const float* b_hh1 = (const float*)d_in[4];
    const float* W_ih2 = (const float*)d_in[5];
    const float* W_hh2 = (const float*)d_in[6];
    const float* b_ih2 = (const float*)d_in[7];
    const float* b_hh2 = (const float*)d_in[8];
    const float* W_lin = (const float*)d_in[9];
    const float* b_lin = (const float*)d_in[10];

    lstm_dp_kernel<<<dim3(2048 / BB), dim3(THREADS), 0, stream>>>(
        input, W_ih1, W_hh1, b_ih1, b_hh1,
        W_ih2, W_hh2, b_ih2, b_hh2, W_lin, b_lin,
        (float*)d_out);
}

// Round 9
// 4447.756 us; speedup vs baseline: 4.2964x; 4.2964x over previous
//
#include <hip/hip_runtime.h>

#define H 51
#define TSEQ 2048
#define BB 4             // batch per block (MFMA cols 4..15 pad) -> 512 blocks, 2 blocks/CU
#define THREADS 512      // 8 waves, 2 tile-slots each; 4 waves/SIMD via 2 resident blocks

typedef _Float16 __attribute__((ext_vector_type(8))) half8;  // 8 f16 (MFMA A/B frag)
typedef float    __attribute__((ext_vector_type(4))) float4v;

#define LOG2E    1.44269504f
#define TWOLOG2E 2.88539008f
#define INV4096  0.000244140625f

__device__ __forceinline__ float sig_pre(float u) {   // sigmoid(g), u = g*log2e
    return __builtin_amdgcn_rcpf(1.0f + __builtin_amdgcn_exp2f(-u));
}
__device__ __forceinline__ float tanh_pre(float u) {  // tanh(g),  u = g*2log2e
    return 1.0f - 2.0f * __builtin_amdgcn_rcpf(1.0f + __builtin_amdgcn_exp2f(u));
}

// R7 structure (rotated schedule, single-plane f16 h, split-f16 weights) at
// BB=4 / 512 blocks. __launch_bounds__(512,2): DO NOT raise the min-wave arg —
// (512,4) caps VGPR at ~64, spills the persistent weight frags, and turns the
// kernel into a 67 GB/dispatch HBM streamer (R8: 19ms). At ~104 VGPR the HW
// still fits 2 blocks/CU (4 waves/SIMD, 416<=512 regs, 40<=160 KB LDS), giving
// two INDEPENDENT barriers per SIMD whose phases interleave.
__global__ __launch_bounds__(THREADS, 2)
void lstm_dp2_kernel(const float* __restrict__ input,
                     const float* __restrict__ W_ih1, const float* __restrict__ W_hh1,
                     const float* __restrict__ b_ih1, const float* __restrict__ b_hh1,
                     const float* __restrict__ W_ih2, const float* __restrict__ W_hh2,
                     const float* __restrict__ b_ih2, const float* __restrict__ b_hh2,
                     const float* __restrict__ W_lin, const float* __restrict__ b_lin,
                     float* __restrict__ out)
{
    // [parity][kstep][fraglane], single f16 plane; k-pad (k>=51) inert
    __shared__ half8 hb1[2][2][64];
    __shared__ half8 hb2[2][2][64];
    __shared__ float h2f[2][64 * 16];     // fp32 h2 (padded j<64) for y
    __shared__ float xss[2][64 * 5 + 16]; // x chunks [i*5+b], +16 pad for n>=4 reads
    __shared__ float ybf[BB][64];         // y buffer (wave7-private)
    __shared__ float wlin[H + 1];

    const int tid  = threadIdx.x;
    const int wv   = tid >> 6;            // 0..7
    const int lane = tid & 63;
    const int n    = lane & 15;           // MFMA col; batch if n<BB
    const int qd   = lane >> 4;           // quad
    const int b0   = blockIdx.x * BB;

    if (tid < 256) {                      // zero both parities (256 half8 per array)
        half8 z = {0,0,0,0,0,0,0,0};
        (&hb1[0][0][0])[tid] = z;
        (&hb2[0][0][0])[tid] = z;
    }
    if (tid < H)  wlin[tid] = W_lin[tid];
    if (tid == H) wlin[H]   = b_lin[0];

    // x chunk 0: 64 steps x 4 batch = 256 elems
    if (tid < 256) {
        int i = tid >> 2, b = tid & 3;
        xss[0][i * 5 + b] = input[(size_t)(b0 + b) * TSEQ + i];
    }

    // ---- persistent A-fragments, split f16 (lo pre-scaled x4096), pre-scaled gates ----
    half8 wa1h[2][2], wa1l[2][2];         // W_hh1 (K=64)
    half8 wa2h[2][4], wa2l[2][4];         // s<2: W_ih2 (k=h1); s>=2: W_hh2 (k=h2)
#pragma unroll
    for (int i = 0; i < 2; ++i) {
        const int tile = wv + 8 * i;      // tiles 13..15 dummy (zero weights)
        const int arow = tile * 16 + n;
        const int cell = arow >> 2, gate = arow & 3;
        const int orow = gate * H + cell;
        const float gsc = (gate == 2) ? TWOLOG2E : LOG2E;
        const bool rok = (arow < 4 * H);
#pragma unroll
        for (int s = 0; s < 2; ++s) {
#pragma unroll
            for (int j = 0; j < 8; ++j) {
                int kk = s * 32 + qd * 8 + j;
                float w = (rok && kk < H) ? gsc * W_hh1[orow * H + kk] : 0.f;
                _Float16 hi = (_Float16)w;
                wa1h[i][s][j] = hi;
                wa1l[i][s][j] = (_Float16)((w - (float)hi) * 4096.f);
            }
        }
#pragma unroll
        for (int s = 0; s < 4; ++s) {
#pragma unroll
            for (int j = 0; j < 8; ++j) {
                int kk = s * 32 + qd * 8 + j;
                float w = 0.f;
                if (rok) {
                    if (kk < H)                       w = gsc * W_ih2[orow * H + kk];
                    else if (kk >= 64 && kk < 64 + H) w = gsc * W_hh2[orow * H + (kk - 64)];
                }
                _Float16 hi = (_Float16)w;
                wa2h[i][s][j] = hi;
                wa2l[i][s][j] = (_Float16)((w - (float)hi) * 4096.f);
            }
        }
    }

    // ---- per-lane elementwise constants (cell j = tile*4 + quad, j<64) ----
    float4v bias1v[2], wih1v[2], bias2v[2];
    int jj[2];
    bool tok[2];
#pragma unroll
    for (int i = 0; i < 2; ++i) {
        const int tile = wv + 8 * i;
        tok[i] = (tile < 13);             // wave-uniform: real tile?
        const int j = tile * 4 + qd;
        jj[i] = j;
        const bool cok = (j < H);
#pragma unroll
        for (int r = 0; r < 4; ++r) {
            const float gsc = (r == 2) ? TWOLOG2E : LOG2E;
            const int orow = r * H + j;
            bias1v[i][r] = cok ? gsc * (b_ih1[orow] + b_hh1[orow]) : 0.f;
            wih1v[i][r]  = cok ? gsc * W_ih1[orow] : 0.f;
            bias2v[i][r] = cok ? gsc * (b_ih2[orow] + b_hh2[orow]) : 0.f;
        }
    }

    float c1[2] = {0.f, 0.f};
    float c2[2] = {0.f, 0.f};

    __syncthreads();   // zeros + wlin + x chunk 0 visible

    // ---- prologue: h1(0) = ew(bias1 + Wih1*x(0))   (h1(-1)=0 -> no MFMA) ----
    {
        const float xb = xss[0][n];       // n>=4 reads pad: finite, inert
#pragma unroll
        for (int i = 0; i < 2; ++i) if (tok[i]) {
            float4v a;
#pragma unroll
            for (int r = 0; r < 4; ++r) a[r] = fmaf(wih1v[i][r], xb, bias1v[i][r]);
            float cn = fmaf(sig_pre(a[1]), c1[i], sig_pre(a[0]) * tanh_pre(a[2]));
            c1[i] = cn;
            float h = sig_pre(a[3]) * tanh_pre(cn * TWOLOG2E);
            int j = jj[i], s = j >> 5, q = (j & 31) >> 3, j7 = j & 7;
            ((_Float16*)&hb1[0][s][q * 16 + n])[j7] = (_Float16)h;
        }
    }
    __syncthreads();   // h1(0) published

#pragma unroll 1
    for (int t = 0; t < TSEQ; ++t) {
        const int p = t & 1;

        // mid-chunk x prefetch (barrier-free double buffer), waves 0-3 only
        if ((t & 63) == 32 && t + 32 < TSEQ && tid < 256) {
            const int cp = (t >> 6) & 1;
            int i = tid >> 2, b = tid & 3;
            xss[cp ^ 1][i * 5 + b] = input[(size_t)(b0 + b) * TSEQ + (t + 32) + i];
        }

        // ---- frag loads: h1(t) [parity p], h2(t-1) [parity p^1] — 4 b128 ----
        half8 g1[2], g2[2];
#pragma unroll
        for (int s = 0; s < 2; ++s) {
            g1[s] = hb1[p][s][lane];
            g2[s] = hb2[p ^ 1][s][lane];
        }

        // ---- y(t-1) + chunk flush: wave7 only ----
        if (wv == 7 && t > 0) {
            const int b = lane & 15, kg = lane >> 4;
            float a = 0.f;
#pragma unroll
            for (int it = 0; it < 13; ++it) {
                int j = kg + it * 4;
                if (j < H) a = fmaf(wlin[j], h2f[p ^ 1][j * 16 + b], a);
            }
            a += __shfl_xor(a, 16, 64);
            a += __shfl_xor(a, 32, 64);
            if (kg == 0 && b < BB) ybf[b][(t - 1) & 63] = a + wlin[H];
            if ((t & 63) == 0) {          // flush y[t-64 .. t-1]
                int tb = t - 64;
#pragma unroll
                for (int r = 0; r < BB; ++r)
                    out[(size_t)(b0 + r) * TSEQ + tb + lane] = ybf[r][lane];
            }
        }

        // ======== chain A: mm2(t)  (g1=h1(t), g2=h2(t-1)) ========
        float4v a2[2], a2l[2];
#pragma unroll
        for (int i = 0; i < 2; ++i) {
            a2[i]  = bias2v[i];
            a2l[i] = (float4v){0.f, 0.f, 0.f, 0.f};
        }
#pragma unroll
        for (int s = 0; s < 2; ++s)
#pragma unroll
            for (int i = 0; i < 2; ++i) {
                a2[i]  = __builtin_amdgcn_mfma_f32_16x16x32_f16(wa2h[i][s],     g1[s], a2[i],  0, 0, 0);
                a2l[i] = __builtin_amdgcn_mfma_f32_16x16x32_f16(wa2l[i][s],     g1[s], a2l[i], 0, 0, 0);
                a2[i]  = __builtin_amdgcn_mfma_f32_16x16x32_f16(wa2h[i][s + 2], g2[s], a2[i],  0, 0, 0);
                a2l[i] = __builtin_amdgcn_mfma_f32_16x16x32_f16(wa2l[i][s + 2], g2[s], a2l[i], 0, 0, 0);
            }

        // ======== chain B: mm1(t+1)  (g1=h1(t), x(t+1)) ========
        const int t1 = t + 1;
        const float xb = xss[(t1 >> 6) & 1][(t1 & 63) * 5 + n];
        float4v a1[2], a1l[2];
#pragma unroll
        for (int i = 0; i < 2; ++i) {
#pragma unroll
            for (int r = 0; r < 4; ++r)
                a1[i][r] = fmaf(wih1v[i][r], xb, bias1v[i][r]);
            a1l[i] = (float4v){0.f, 0.f, 0.f, 0.f};
        }
#pragma unroll
        for (int s = 0; s < 2; ++s)
#pragma unroll
            for (int i = 0; i < 2; ++i) {
                a1[i]  = __builtin_amdgcn_mfma_f32_16x16x32_f16(wa1h[i][s], g1[s], a1[i],  0, 0, 0);
                a1l[i] = __builtin_amdgcn_mfma_f32_16x16x32_f16(wa1l[i][s], g1[s], a1l[i], 0, 0, 0);
            }

        // ---- ew2 -> hb2[p], h2f[p] (dummy tiles skipped, wave-uniform) ----
#pragma unroll
        for (int i = 0; i < 2; ++i) if (tok[i]) {
#pragma unroll
            for (int r = 0; r < 4; ++r)
                a2[i][r] = fmaf(a2l[i][r], INV4096, a2[i][r]);
            float cn = fmaf(sig_pre(a2[i][1]), c2[i], sig_pre(a2[i][0]) * tanh_pre(a2[i][2]));
            c2[i] = cn;
            float h = sig_pre(a2[i][3]) * tanh_pre(cn * TWOLOG2E);
            int j = jj[i], s = j >> 5, q = (j & 31) >> 3, j7 = j & 7;
            ((_Float16*)&hb2[p][s][q * 16 + n])[j7] = (_Float16)h;
            h2f[p][j * 16 + n] = h;
        }

        // ---- ew1 -> hb1[p^1] ----
#pragma unroll
        for (int i = 0; i < 2; ++i) if (tok[i]) {
#pragma unroll
            for (int r = 0; r < 4; ++r)
                a1[i][r] = fmaf(a1l[i][r], INV4096, a1[i][r]);
            float cn = fmaf(sig_pre(a1[i][1]), c1[i], sig_pre(a1[i][0]) * tanh_pre(a1[i][2]));
            c1[i] = cn;
            float h = sig_pre(a1[i][3]) * tanh_pre(cn * TWOLOG2E);
            int j = jj[i], s = j >> 5, q = (j & 31) >> 3, j7 = j & 7;
            ((_Float16*)&hb1[p ^ 1][s][q * 16 + n])[j7] = (_Float16)h;
        }

        __syncthreads();   // publishes h2(t), h2f(t), h1(t+1)
    }

    // ---- epilogue: y(2047) + final chunk flush ----
    if (wv == 7) {
        const int b = lane & 15, kg = lane >> 4;
        float a = 0.f;
#pragma unroll
        for (int it = 0; it < 13; ++it) {
            int j = kg + it * 4;
            if (j < H) a = fmaf(wlin[j], h2f[1][j * 16 + b], a);
        }
        a += __shfl_xor(a, 16, 64);
        a += __shfl_xor(a, 32, 64);
        if (kg == 0 && b < BB) ybf[b][63] = a + wlin[H];
#pragma unroll
        for (int r = 0; r < BB; ++r)
            out[(size_t)(b0 + r) * TSEQ + (TSEQ - 64) + lane] = ybf[r][lane];
    }
}

extern "C" void kernel_launch(void* const* d_in, const int* in_sizes, int n_in,
                              void* d_out, int out_size, void* d_ws, size_t ws_size,
                              hipStream_t stream) {
    const float* input = (const float*)d_in[0];
    const float* W_ih1 = (const float*)d_in[1];
    const float* W_hh1 = (const float*)d_in[2];
    const float* b_ih1 = (const float*)d_in[3];
    const float* b_hh1 = (const float*)d_in[4];
    const float* W_ih2 = (const float*)d_in[5];
    const float* W_hh2 = (const float*)d_in[6];
    const float* b_ih2 = (const float*)d_in[7];
    const float* b_hh2 = (const float*)d_in[8];
    const float* W_lin = (const float*)d_in[9];
    const float* b_lin = (const float*)d_in[10];

    lstm_dp2_kernel<<<dim3(2048 / BB), dim3(THREADS), 0, stream>>>(
        input, W_ih1, W_hh1, b_ih1, b_hh1,
        W_ih2, W_hh2, b_ih2, b_hh2, W_lin, b_lin,
        (float*)d_out);
}

// Round 10
// 1652.034 us; speedup vs baseline: 11.5672x; 2.6923x over previous
//
#include <hip/hip_runtime.h>

#define H 51
#define TSEQ 2048
#define BB 16            // batch per block — fills all 16 MFMA columns
#define THREADS 1024     // 16 waves: 0-12 = tiles, 13 = y, 14-15 = x prefetch
                         // one block/CU -> 4 waves/SIMD structurally

typedef _Float16 __attribute__((ext_vector_type(8))) half8;  // 8 f16 (MFMA A/B frag)
typedef float    __attribute__((ext_vector_type(4))) float4v;

#define LOG2E    1.44269504f
#define TWOLOG2E 2.88539008f

__device__ __forceinline__ float sig_pre(float u) {   // sigmoid(g), u = g*log2e
    return __builtin_amdgcn_rcpf(1.0f + __builtin_amdgcn_exp2f(-u));
}
__device__ __forceinline__ float tanh_pre(float u) {  // tanh(g),  u = g*2log2e
    return 1.0f - 2.0f * __builtin_amdgcn_rcpf(1.0f + __builtin_amdgcn_exp2f(u));
}

// R7 rotated single-barrier schedule, widened to 16 waves x 1 tile-slot.
// PLAIN f16 weights (no hi/lo split) to keep regs <=128 so the 1024-thread
// block launches at 4 waves/SIMD. h single f16 plane (R7-proven). Gate rows
// pre-scaled by log2e / 2log2e. A rows repacked [i,f,g,o] per cell -> C/D reg
// r == gate r, cell = wv*4 + quad. Dummy cells (j>=51) write into k-pad LDS
// slots whose A-columns are zero -> inert.
__global__ __launch_bounds__(THREADS)
void lstm_w16_kernel(const float* __restrict__ input,
                     const float* __restrict__ W_ih1, const float* __restrict__ W_hh1,
                     const float* __restrict__ b_ih1, const float* __restrict__ b_hh1,
                     const float* __restrict__ W_ih2, const float* __restrict__ W_hh2,
                     const float* __restrict__ b_ih2, const float* __restrict__ b_hh2,
                     const float* __restrict__ W_lin, const float* __restrict__ b_lin,
                     float* __restrict__ out)
{
    // [parity][kstep][fraglane], single f16 plane; k-pad (k>=51) inert
    __shared__ half8 hb1[2][2][64];
    __shared__ half8 hb2[2][2][64];
    __shared__ float h2f[2][64 * 16];    // fp32 h2 (padded j<64) for y
    __shared__ float xss[2][64 * 17];    // x chunks [i*17+b], conflict-free stride
    __shared__ float ybf[BB][64];        // y buffer (wave13-private)
    __shared__ float wlin[H + 1];

    const int tid  = threadIdx.x;
    const int wv   = tid >> 6;           // 0..15
    const int lane = tid & 63;
    const int n    = lane & 15;          // MFMA col = batch
    const int qd   = lane >> 4;          // quad
    const int b0   = blockIdx.x * BB;
    const bool tok = (wv < 13);          // real tile?

    if (tid < 256) {                     // zero both parities (256 half8 per array)
        half8 z = {0,0,0,0,0,0,0,0};
        (&hb1[0][0][0])[tid] = z;
        (&hb2[0][0][0])[tid] = z;
    }
    if (tid < H)  wlin[tid] = W_lin[tid];
    if (tid == H) wlin[H]   = b_lin[0];

    // x chunk 0: waves 14-15, coalesced (each wave: 8 batch rows x 64 steps)
    if (wv >= 14) {
#pragma unroll
        for (int k = 0; k < 8; ++k) {
            int b = (wv - 14) * 8 + k;
            xss[0][lane * 17 + b] = input[(size_t)(b0 + b) * TSEQ + lane];
        }
    }

    // ---- persistent A-fragments, PLAIN f16, gate rows pre-scaled ----
    half8 wa1[2];                        // W_hh1 (K=64)
    half8 wa2[4];                        // s<2: W_ih2 (k=h1); s>=2: W_hh2 (k=h2)
    {
        const int arow = wv * 16 + n;    // tile = wv; waves 13-15 get zeros
        const int cell = arow >> 2, gate = arow & 3;
        const int orow = gate * H + cell;
        const float gsc = (gate == 2) ? TWOLOG2E : LOG2E;
        const bool rok = (arow < 4 * H);
#pragma unroll
        for (int s = 0; s < 2; ++s)
#pragma unroll
            for (int j = 0; j < 8; ++j) {
                int kk = s * 32 + qd * 8 + j;
                wa1[s][j] = (_Float16)((rok && kk < H) ? gsc * W_hh1[orow * H + kk] : 0.f);
            }
#pragma unroll
        for (int s = 0; s < 4; ++s)
#pragma unroll
            for (int j = 0; j < 8; ++j) {
                int kk = s * 32 + qd * 8 + j;
                float w = 0.f;
                if (rok) {
                    if (kk < H)                       w = gsc * W_ih2[orow * H + kk];
                    else if (kk >= 64 && kk < 64 + H) w = gsc * W_hh2[orow * H + (kk - 64)];
                }
                wa2[s][j] = (_Float16)w;
            }
    }

    // ---- per-lane elementwise constants (cell j = wv*4 + quad, j<64) ----
    float4v bias1v, wih1v, bias2v;
    const int jj = wv * 4 + qd;
    {
        const bool cok = tok && (jj < H);
#pragma unroll
        for (int r = 0; r < 4; ++r) {
            const float gsc = (r == 2) ? TWOLOG2E : LOG2E;
            const int orow = r * H + jj;
            bias1v[r] = cok ? gsc * (b_ih1[orow] + b_hh1[orow]) : 0.f;
            wih1v[r]  = cok ? gsc * W_ih1[orow] : 0.f;
            bias2v[r] = cok ? gsc * (b_ih2[orow] + b_hh2[orow]) : 0.f;
        }
    }

    float c1 = 0.f, c2 = 0.f;

    __syncthreads();   // zeros + wlin + x chunk 0 visible

    // ---- prologue: h1(0) = ew(bias1 + Wih1*x(0))   (h1(-1)=0 -> no MFMA) ----
    if (tok) {
        const float xb = xss[0][n];
        float4v a;
#pragma unroll
        for (int r = 0; r < 4; ++r) a[r] = fmaf(wih1v[r], xb, bias1v[r]);
        float cn = fmaf(sig_pre(a[1]), c1, sig_pre(a[0]) * tanh_pre(a[2]));
        c1 = cn;
        float h = sig_pre(a[3]) * tanh_pre(cn * TWOLOG2E);
        int s = jj >> 5, q = (jj & 31) >> 3, j7 = jj & 7;
        ((_Float16*)&hb1[0][s][q * 16 + n])[j7] = (_Float16)h;
    }
    __syncthreads();   // h1(0) published

#pragma unroll 1
    for (int t = 0; t < TSEQ; ++t) {
        const int p = t & 1;

        if (tok) {
            // ---- frag loads: h1(t) [parity p], h2(t-1) [parity p^1] ----
            half8 g1[2], g2[2];
#pragma unroll
            for (int s = 0; s < 2; ++s) {
                g1[s] = hb1[p][s][lane];
                g2[s] = hb2[p ^ 1][s][lane];
            }

            // ---- chain A: mm2(t) ----
            float4v a2 = bias2v;
#pragma unroll
            for (int s = 0; s < 2; ++s) {
                a2 = __builtin_amdgcn_mfma_f32_16x16x32_f16(wa2[s],     g1[s], a2, 0, 0, 0);
                a2 = __builtin_amdgcn_mfma_f32_16x16x32_f16(wa2[s + 2], g2[s], a2, 0, 0, 0);
            }

            // ---- chain B: mm1(t+1)  (t=2047 writes never-read h1(2048)) ----
            const int t1 = t + 1;
            const float xb = xss[(t1 >> 6) & 1][(t1 & 63) * 17 + n];
            float4v a1;
#pragma unroll
            for (int r = 0; r < 4; ++r) a1[r] = fmaf(wih1v[r], xb, bias1v[r]);
#pragma unroll
            for (int s = 0; s < 2; ++s)
                a1 = __builtin_amdgcn_mfma_f32_16x16x32_f16(wa1[s], g1[s], a1, 0, 0, 0);

            // ---- ew2 -> hb2[p], h2f[p] ----
            {
                float cn = fmaf(sig_pre(a2[1]), c2, sig_pre(a2[0]) * tanh_pre(a2[2]));
                c2 = cn;
                float h = sig_pre(a2[3]) * tanh_pre(cn * TWOLOG2E);
                int s = jj >> 5, q = (jj & 31) >> 3, j7 = jj & 7;
                ((_Float16*)&hb2[p][s][q * 16 + n])[j7] = (_Float16)h;
                h2f[p][jj * 16 + n] = h;
            }
            // ---- ew1 -> hb1[p^1] ----
            {
                float cn = fmaf(sig_pre(a1[1]), c1, sig_pre(a1[0]) * tanh_pre(a1[2]));
                c1 = cn;
                float h = sig_pre(a1[3]) * tanh_pre(cn * TWOLOG2E);
                int s = jj >> 5, q = (jj & 31) >> 3, j7 = jj & 7;
                ((_Float16*)&hb1[p ^ 1][s][q * 16 + n])[j7] = (_Float16)h;
            }
        } else if (wv == 13) {
            // ---- y(t-1) + chunk flush (off the real waves' path) ----
            if (t > 0) {
                const int b = lane & 15, kg = lane >> 4;
                float a = 0.f;
#pragma unroll
                for (int it = 0; it < 13; ++it) {
                    int j = kg + it * 4;
                    if (j < H) a = fmaf(wlin[j], h2f[p ^ 1][j * 16 + b], a);
                }
                a += __shfl_xor(a, 16, 64);
                a += __shfl_xor(a, 32, 64);
                if (kg == 0) ybf[b][(t - 1) & 63] = a + wlin[H];
                if ((t & 63) == 0) {      // flush y[t-64 .. t-1]
                    int tb = t - 64;
#pragma unroll
                    for (int r = 0; r < BB; ++r)
                        out[(size_t)(b0 + r) * TSEQ + tb + lane] = ybf[r][lane];
                }
            }
        } else {
            // ---- waves 14-15: x prefetch at mid-chunk ----
            if ((t & 63) == 32 && t + 32 < TSEQ) {
                const int cp = (t >> 6) & 1;
#pragma unroll
                for (int k = 0; k < 8; ++k) {
                    int b = (wv - 14) * 8 + k;
                    xss[cp ^ 1][lane * 17 + b] = input[(size_t)(b0 + b) * TSEQ + (t + 32) + lane];
                }
            }
        }

        __syncthreads();   // publishes h2(t), h2f(t), h1(t+1)
    }

    // ---- epilogue: y(2047) + final chunk flush ----
    if (wv == 13) {
        const int b = lane & 15, kg = lane >> 4;
        float a = 0.f;
#pragma unroll
        for (int it = 0; it < 13; ++it) {
            int j = kg + it * 4;
            if (j < H) a = fmaf(wlin[j], h2f[1][j * 16 + b], a);
        }
        a += __shfl_xor(a, 16, 64);
        a += __shfl_xor(a, 32, 64);
        if (kg == 0) ybf[b][63] = a + wlin[H];
#pragma unroll
        for (int r = 0; r < BB; ++r)
            out[(size_t)(b0 + r) * TSEQ + (TSEQ - 64) + lane] = ybf[r][lane];
    }
}

extern "C" void kernel_launch(void* const* d_in, const int* in_sizes, int n_in,
                              void* d_out, int out_size, void* d_ws, size_t ws_size,
                              hipStream_t stream) {
    const float* input = (const float*)d_in[0];
    const float* W_ih1 = (const float*)d_in[1];
    const float* W_hh1 = (const float*)d_in[2];
    const float* b_ih1 = (const float*)d_in[3];
    const float* b_hh1 = (const float*)d_in[4];
    const float* W_ih2 = (const float*)d_in[5];
    const float* W_hh2 = (const float*)d_in[6];
    const float* b_ih2 = (const float*)d_in[7];
    const float* b_hh2 = (const float*)d_in[8];
    const float* W_lin = (const float*)d_in[9];
    const float* b_lin = (const float*)d_in[10];

    lstm_w16_kernel<<<dim3(2048 / BB), dim3(THREADS), 0, stream>>>(
        input, W_ih1, W_hh1, b_ih1, b_hh1,
        W_ih2, W_hh2, b_ih2, b_hh2, W_lin, b_lin,
        (float*)d_out);
}

// Round 11
// 1559.237 us; speedup vs baseline: 12.2557x; 1.0595x over previous
//
#include <hip/hip_runtime.h>

#define H 51
#define TSEQ 2048
#define BB 16            // batch per block — fills all 16 MFMA columns
#define THREADS 1024     // 16 waves: 0-12 = tiles, 13 = y, 14-15 = x prefetch

typedef _Float16 __attribute__((ext_vector_type(8))) half8;  // 8 f16 (MFMA A/B frag)
typedef float    __attribute__((ext_vector_type(4))) float4v;

#define LOG2E    1.44269504f
#define TWOLOG2E 2.88539008f

__device__ __forceinline__ float sig_pre(float u) {   // sigmoid(g), u = g*log2e
    return __builtin_amdgcn_rcpf(1.0f + __builtin_amdgcn_exp2f(-u));
}
__device__ __forceinline__ float tanh_pre(float u) {  // tanh(g),  u = g*2log2e
    return 1.0f - 2.0f * __builtin_amdgcn_rcpf(1.0f + __builtin_amdgcn_exp2f(u));
}

// R10 structure (16 waves x 1 tile, plain-f16 weights, single-plane f16 h,
// rotated single-barrier schedule) + latency trims:
//  - frag reads issued together; mm1 (needs only g1 = first 2 reads, LDS
//    returns in-order -> lgkmcnt(2)) runs while g2 drains
//  - mm2 chain split into two depth-2 accumulators + one vector add
//  - loop unrolled x2 so parity indices are immediates
__global__ __launch_bounds__(THREADS)
void lstm_w16b_kernel(const float* __restrict__ input,
                      const float* __restrict__ W_ih1, const float* __restrict__ W_hh1,
                      const float* __restrict__ b_ih1, const float* __restrict__ b_hh1,
                      const float* __restrict__ W_ih2, const float* __restrict__ W_hh2,
                      const float* __restrict__ b_ih2, const float* __restrict__ b_hh2,
                      const float* __restrict__ W_lin, const float* __restrict__ b_lin,
                      float* __restrict__ out)
{
    __shared__ half8 hb1[2][2][64];      // [parity][kstep][fraglane]
    __shared__ half8 hb2[2][2][64];
    __shared__ float h2f[2][64 * 16];    // fp32 h2 (padded j<64) for y
    __shared__ float xss[2][64 * 17];    // x chunks [i*17+b]
    __shared__ float ybf[BB][64];        // y buffer (wave13-private)
    __shared__ float wlin[H + 1];

    const int tid  = threadIdx.x;
    const int wv   = tid >> 6;           // 0..15
    const int lane = tid & 63;
    const int n    = lane & 15;          // MFMA col = batch
    const int qd   = lane >> 4;          // quad
    const int b0   = blockIdx.x * BB;
    const bool tok = (wv < 13);          // real tile?

    if (tid < 256) {
        half8 z = {0,0,0,0,0,0,0,0};
        (&hb1[0][0][0])[tid] = z;
        (&hb2[0][0][0])[tid] = z;
    }
    if (tid < H)  wlin[tid] = W_lin[tid];
    if (tid == H) wlin[H]   = b_lin[0];

    if (wv >= 14) {                      // x chunk 0
#pragma unroll
        for (int k = 0; k < 8; ++k) {
            int b = (wv - 14) * 8 + k;
            xss[0][lane * 17 + b] = input[(size_t)(b0 + b) * TSEQ + lane];
        }
    }

    // ---- persistent A-fragments, plain f16, gate rows pre-scaled ----
    half8 wa1[2];                        // W_hh1 (K=64)
    half8 wa2[4];                        // s<2: W_ih2 (k=h1); s>=2: W_hh2 (k=h2)
    {
        const int arow = wv * 16 + n;    // tile = wv; waves 13-15 get zeros
        const int cell = arow >> 2, gate = arow & 3;
        const int orow = gate * H + cell;
        const float gsc = (gate == 2) ? TWOLOG2E : LOG2E;
        const bool rok = (arow < 4 * H);
#pragma unroll
        for (int s = 0; s < 2; ++s)
#pragma unroll
            for (int j = 0; j < 8; ++j) {
                int kk = s * 32 + qd * 8 + j;
                wa1[s][j] = (_Float16)((rok && kk < H) ? gsc * W_hh1[orow * H + kk] : 0.f);
            }
#pragma unroll
        for (int s = 0; s < 4; ++s)
#pragma unroll
            for (int j = 0; j < 8; ++j) {
                int kk = s * 32 + qd * 8 + j;
                float w = 0.f;
                if (rok) {
                    if (kk < H)                       w = gsc * W_ih2[orow * H + kk];
                    else if (kk >= 64 && kk < 64 + H) w = gsc * W_hh2[orow * H + (kk - 64)];
                }
                wa2[s][j] = (_Float16)w;
            }
    }

    // ---- per-lane elementwise constants (cell j = wv*4 + quad, j<64) ----
    float4v bias1v, wih1v, bias2v;
    const int jj = wv * 4 + qd;
    {
        const bool cok = tok && (jj < H);
#pragma unroll
        for (int r = 0; r < 4; ++r) {
            const float gsc = (r == 2) ? TWOLOG2E : LOG2E;
            const int orow = r * H + jj;
            bias1v[r] = cok ? gsc * (b_ih1[orow] + b_hh1[orow]) : 0.f;
            wih1v[r]  = cok ? gsc * W_ih1[orow] : 0.f;
            bias2v[r] = cok ? gsc * (b_ih2[orow] + b_hh2[orow]) : 0.f;
        }
    }

    float c1 = 0.f, c2 = 0.f;
    const int js = jj >> 5, jq = (jj & 31) >> 3, j7 = jj & 7;   // h store coords

    __syncthreads();

    // ---- prologue: h1(0) = ew(bias1 + Wih1*x(0)) ----
    if (tok) {
        const float xb = xss[0][n];
        float4v a;
#pragma unroll
        for (int r = 0; r < 4; ++r) a[r] = fmaf(wih1v[r], xb, bias1v[r]);
        float cn = fmaf(sig_pre(a[1]), c1, sig_pre(a[0]) * tanh_pre(a[2]));
        c1 = cn;
        float h = sig_pre(a[3]) * tanh_pre(cn * TWOLOG2E);
        ((_Float16*)&hb1[0][js][jq * 16 + n])[j7] = (_Float16)h;
    }
    __syncthreads();

    // ---- one step at compile-time parity P ----
#define STEP(t, P)                                                              \
    {                                                                           \
        if (tok) {                                                              \
            half8 g1[2], g2[2];                                                 \
            g1[0] = hb1[P][0][lane];      g1[1] = hb1[P][1][lane];              \
            g2[0] = hb2[P ^ 1][0][lane];  g2[1] = hb2[P ^ 1][1][lane];          \
            /* chain B first: mm1(t+1) needs only g1 (lgkmcnt(2)) */            \
            const int t1 = (t) + 1;                                             \
            const float xb = xss[(t1 >> 6) & 1][(t1 & 63) * 17 + n];            \
            float4v a1;                                                         \
            _Pragma("unroll")                                                   \
            for (int r = 0; r < 4; ++r) a1[r] = fmaf(wih1v[r], xb, bias1v[r]);  \
            a1 = __builtin_amdgcn_mfma_f32_16x16x32_f16(wa1[0], g1[0], a1, 0, 0, 0); \
            a1 = __builtin_amdgcn_mfma_f32_16x16x32_f16(wa1[1], g1[1], a1, 0, 0, 0); \
            /* chain A: mm2(t), two depth-2 chains + add */                     \
            float4v a2a = bias2v;                                               \
            float4v a2b = (float4v){0.f, 0.f, 0.f, 0.f};                        \
            a2a = __builtin_amdgcn_mfma_f32_16x16x32_f16(wa2[0], g1[0], a2a, 0, 0, 0); \
            a2b = __builtin_amdgcn_mfma_f32_16x16x32_f16(wa2[2], g2[0], a2b, 0, 0, 0); \
            a2a = __builtin_amdgcn_mfma_f32_16x16x32_f16(wa2[1], g1[1], a2a, 0, 0, 0); \
            a2b = __builtin_amdgcn_mfma_f32_16x16x32_f16(wa2[3], g2[1], a2b, 0, 0, 0); \
            /* ew1 -> hb1[P^1] (a1 ready first) */                              \
            {                                                                   \
                float cn = fmaf(sig_pre(a1[1]), c1, sig_pre(a1[0]) * tanh_pre(a1[2])); \
                c1 = cn;                                                        \
                float h = sig_pre(a1[3]) * tanh_pre(cn * TWOLOG2E);             \
                ((_Float16*)&hb1[P ^ 1][js][jq * 16 + n])[j7] = (_Float16)h;    \
            }                                                                   \
            /* ew2 -> hb2[P], h2f[P] */                                         \
            {                                                                   \
                float4v a2;                                                     \
                _Pragma("unroll")                                               \
                for (int r = 0; r < 4; ++r) a2[r] = a2a[r] + a2b[r];            \
                float cn = fmaf(sig_pre(a2[1]), c2, sig_pre(a2[0]) * tanh_pre(a2[2])); \
                c2 = cn;                                                        \
                float h = sig_pre(a2[3]) * tanh_pre(cn * TWOLOG2E);             \
                ((_Float16*)&hb2[P][js][jq * 16 + n])[j7] = (_Float16)h;        \
                h2f[P][jj * 16 + n] = h;                                        \
            }                                                                   \
        } else if (wv == 13) {                                                  \
            if ((t) > 0) {                                                      \
                const int b = lane & 15, kg = lane >> 4;                        \
                float a = 0.f;                                                  \
                _Pragma("unroll")                                               \
                for (int it = 0; it < 13; ++it) {                               \
                    int j = kg + it * 4;                                        \
                    if (j < H) a = fmaf(wlin[j], h2f[P ^ 1][j * 16 + b], a);    \
                }                                                               \
                a += __shfl_xor(a, 16, 64);                                     \
                a += __shfl_xor(a, 32, 64);                                     \
                if (kg == 0) ybf[b][((t) - 1) & 63] = a + wlin[H];              \
                if (((t) & 63) == 0) {                                          \
                    int tb = (t) - 64;                                          \
                    _Pragma("unroll")                                           \
                    for (int r = 0; r < BB; ++r)                                \
                        out[(size_t)(b0 + r) * TSEQ + tb + lane] = ybf[r][lane]; \
                }                                                               \
            }                                                                   \
        } else {                                                                \
            if (((t) & 63) == 32 && (t) + 32 < TSEQ) {                          \
                const int cp = ((t) >> 6) & 1;                                  \
                _Pragma("unroll")                                               \
                for (int k = 0; k < 8; ++k) {                                   \
                    int b = (wv - 14) * 8 + k;                                  \
                    xss[cp ^ 1][lane * 17 + b] =                                \
                        input[(size_t)(b0 + b) * TSEQ + ((t) + 32) + lane];     \
                }                                                               \
            }                                                                   \
        }                                                                       \
        __syncthreads();                                                        \
    }

#pragma unroll 1
    for (int t = 0; t < TSEQ; t += 2) {
        STEP(t, 0)
        STEP(t + 1, 1)
    }
#undef STEP

    // ---- epilogue: y(2047) + final chunk flush ----
    if (wv == 13) {
        const int b = lane & 15, kg = lane >> 4;
        float a = 0.f;
#pragma unroll
        for (int it = 0; it < 13; ++it) {
            int j = kg + it * 4;
            if (j < H) a = fmaf(wlin[j], h2f[1][j * 16 + b], a);
        }
        a += __shfl_xor(a, 16, 64);
        a += __shfl_xor(a, 32, 64);
        if (kg == 0) ybf[b][63] = a + wlin[H];
#pragma unroll
        for (int r = 0; r < BB; ++r)
            out[(size_t)(b0 + r) * TSEQ + (TSEQ - 64) + lane] = ybf[r][lane];
    }
}

extern "C" void kernel_launch(void* const* d_in, const int* in_sizes, int n_in,
                              void* d_out, int out_size, void* d_ws, size_t ws_size,
                              hipStream_t stream) {
    const float* input = (const float*)d_in[0];
    const float* W_ih1 = (const float*)d_in[1];
    const float* W_hh1 = (const float*)d_in[2];
    const float* b_ih1 = (const float*)d_in[3];
    const float* b_hh1 = (const float*)d_in[4];
    const float* W_ih2 = (const float*)d_in[5];
    const float* W_hh2 = (const float*)d_in[6];
    const float* b_ih2 = (const float*)d_in[7];
    const float* b_hh2 = (const float*)d_in[8];
    const float* W_lin = (const float*)d_in[9];
    const float* b_lin = (const float*)d_in[10];

    lstm_w16b_kernel<<<dim3(2048 / BB), dim3(THREADS), 0, stream>>>(
        input, W_ih1, W_hh1, b_ih1, b_hh1,
        W_ih2, W_hh2, b_ih2, b_hh2, W_lin, b_lin,
        (float*)d_out);
}